// Round 14
// baseline (110.797 us; speedup 1.0000x reference)
//
#include <hip/hip_runtime.h>
#include <math.h>

#define B 32
#define S 8
#define FEA 2560
#define T 800
#define T4 200       // float4 per t-row
#define NCL 512
#define EMB 256
#define H 8

#define TC4 50       // float4 per t-chunk (200 floats)
#define NFQ 4        // f-quarters
#define FPQ 640      // f per quarter
#define NSTEP 160    // f-steps per wave (FPQ / 4 waves)

__device__ __forceinline__ float4 ld4(const float* p) { return *(const float4*)(p); }

__device__ __forceinline__ void fma4(float4& a, const float4 v, const float s) {
    a.x = fmaf(v.x, s, a.x); a.y = fmaf(v.y, s, a.y);
    a.z = fmaf(v.z, s, a.z); a.w = fmaf(v.w, s, a.w);
}

// 8 heads x float4 FMA for one f-row; W slice broadcast from LDS.
#define DO_STEP(Rv, stp) {                                                 \
    const int fl_ = (stp) * 4 + wv_;                                       \
    const float4 wA = smem4[fl_ * 2];                                      \
    const float4 wB = smem4[fl_ * 2 + 1];                                  \
    fma4(acc[0], Rv, wA.x); fma4(acc[1], Rv, wA.y);                        \
    fma4(acc[2], Rv, wA.z); fma4(acc[3], Rv, wA.w);                        \
    fma4(acc[4], Rv, wB.x); fma4(acc[5], Rv, wB.y);                        \
    fma4(acc[6], Rv, wB.z); fma4(acc[7], Rv, wB.w);                        \
}

// ---------------- Kernel A: y[b,h,t] = sum_f W_w[h,f]*x[b,f,t]  (fq-partials) ----------------
// grid (17, 32): x<16 -> (tc = x&3, fq = x>>2); x==16 & b<8 -> u blocks.
__global__ __launch_bounds__(256) void proj_u_kernel(const float* __restrict__ x,
                                                     const float* __restrict__ W_w,
                                                     const float* __restrict__ U_w,
                                                     const float* __restrict__ U_b,
                                                     const float* __restrict__ m,
                                                     float* __restrict__ y_part,
                                                     float* __restrict__ u_out) {
    const int b = blockIdx.y;

    if (blockIdx.x == 16) {
        if (b >= 8) return;
        const int n  = b * 64 + (threadIdx.x >> 2);
        const int h0 = (threadIdx.x & 3) * 2;
        float a0 = 0.f, a1 = 0.f;
        #pragma unroll 4
        for (int e = 0; e < EMB; ++e) {
            const float mv = m[n * EMB + e];
            a0 += mv * U_w[h0 * EMB + e];
            a1 += mv * U_w[(h0 + 1) * EMB + e];
        }
        u_out[n * H + h0]     = a0 + U_b[h0];
        u_out[n * H + h0 + 1] = a1 + U_b[h0 + 1];
        return;
    }

    __shared__ float4 smem4[1600];           // 25.6 KB: W slice [640][8] then reduce buf
    float* wlds = (float*)smem4;

    const int tid = threadIdx.x, wv_ = tid >> 6, lane = tid & 63;
    const int tc = blockIdx.x & 3, fq = blockIdx.x >> 2;
    const int fbase = fq * FPQ;

    // stage W_w slice transposed: wlds[fi*8+h] = W_w[h][fbase+fi]
    for (int i = tid; i < FPQ * H; i += 256) {
        const int h = i / FPQ, fi = i % FPQ;
        wlds[fi * 8 + h] = W_w[h * FEA + fbase + fi];
    }
    __syncthreads();

    const int l4 = (lane < TC4) ? lane : (TC4 - 1);   // idle lanes duplicate lane 49
    const float* xp = x + (size_t)b * FEA * T + (size_t)(fbase + wv_) * T
                        + tc * 200 + l4 * 4;
    const size_t fstride = (size_t)4 * T;             // floats between steps

    float4 acc[8];
    #pragma unroll
    for (int h = 0; h < 8; ++h) acc[h] = make_float4(0.f, 0.f, 0.f, 0.f);

    float4 Rc = ld4(xp);
    float4 Rn = ld4(xp + fstride);

    // ---- main loop: zero barriers, depth-2 register prefetch, 800B-run loads ----
    #pragma unroll 1
    for (int step = 0; step < NSTEP; step += 2) {
        DO_STEP(Rc, step)
        if (step + 2 < NSTEP) Rc = ld4(xp + fstride * (step + 2));
        DO_STEP(Rn, step + 1)
        if (step + 3 < NSTEP) Rn = ld4(xp + fstride * (step + 3));
    }

    // ---- block reduction over the 4 waves' f-ranges ----
    __syncthreads();                                  // done reading wlds region
    if (lane < TC4) {
        #pragma unroll
        for (int h = 0; h < 8; ++h)
            smem4[(wv_ * 8 + h) * TC4 + lane] = acc[h];
    }
    __syncthreads();
    float4* y4 = (float4*)y_part;
    for (int c = tid; c < 8 * TC4; c += 256) {
        float4 s0 = smem4[c];
        #pragma unroll
        for (int w2 = 1; w2 < 4; ++w2) {
            const float4 v = smem4[w2 * 400 + c];
            s0.x += v.x; s0.y += v.y; s0.z += v.z; s0.w += v.w;
        }
        const int h = c / TC4, l = c % TC4;
        y4[(((size_t)fq * B + b) * H + h) * T4 + tc * TC4 + l] = s0;
    }
}

// ---------------- Kernel B: per (b,s): denom, w, gate, e = a @ m ----------------
__global__ __launch_bounds__(256) void wgate_e_kernel(const float* __restrict__ y_part,
                                                      const float* __restrict__ mask,
                                                      const float* __restrict__ W_b,
                                                      const float* __restrict__ u_buf,
                                                      const float* __restrict__ v_w,
                                                      const float* __restrict__ v_b,
                                                      const float* __restrict__ m,
                                                      float* __restrict__ out) {
    __shared__ float a_lds[NCL];
    __shared__ float wred[4][12];
    __shared__ float tot[12];
    __shared__ float w_sh[8];

    const int bs = blockIdx.x, b = bs >> 3;
    const int tid = threadIdx.x, wv_ = tid >> 6, lane = tid & 63;
    const float4* mk4 = (const float4*)mask;
    const float4* y4  = (const float4*)y_part;

    float wp[9];
    #pragma unroll
    for (int i = 0; i < 9; ++i) wp[i] = 0.f;

    if (tid < T4) {
        const float4 mk = mk4[(size_t)bs * T4 + tid];
        wp[8] = mk.x + mk.y + mk.z + mk.w;
        #pragma unroll
        for (int h = 0; h < 8; ++h) {
            float4 ys = y4[(((size_t)b) * H + h) * T4 + tid];
            #pragma unroll
            for (int fq = 1; fq < NFQ; ++fq) {
                const float4 v = y4[(((size_t)fq * B + b) * H + h) * T4 + tid];
                ys.x += v.x; ys.y += v.y; ys.z += v.z; ys.w += v.w;
            }
            wp[h] = mk.x * ys.x + mk.y * ys.y + mk.z * ys.z + mk.w * ys.w;
        }
    }
    #pragma unroll
    for (int i = 0; i < 9; ++i) {
        float v = wp[i];
        #pragma unroll
        for (int off = 32; off > 0; off >>= 1) v += __shfl_xor(v, off, 64);
        if (lane == 0) wred[wv_][i] = v;
    }
    __syncthreads();
    if (tid < 9) tot[tid] = wred[0][tid] + wred[1][tid] + wred[2][tid] + wred[3][tid];
    __syncthreads();
    if (tid < 8) w_sh[tid] = tot[tid] / (tot[8] + 1e-10f) + W_b[tid];
    __syncthreads();

    const float vb = v_b[0];
    float vw[8];
    #pragma unroll
    for (int h = 0; h < 8; ++h) vw[h] = v_w[h];
    #pragma unroll
    for (int k = 0; k < 2; ++k) {
        const int n = k * 256 + tid;
        float c = vb;
        #pragma unroll
        for (int h = 0; h < 8; ++h)
            c += tanhf(w_sh[h] + u_buf[n * H + h]) * vw[h];
        a_lds[n] = 1.f / (1.f + expf(-c));
    }
    __syncthreads();

    float e = 0.f;
    #pragma unroll 8
    for (int n = 0; n < NCL; ++n) e += a_lds[n] * m[n * EMB + tid];
    out[bs * EMB + tid] = e;
}

extern "C" void kernel_launch(void* const* d_in, const int* in_sizes, int n_in,
                              void* d_out, int out_size, void* d_ws, size_t ws_size,
                              hipStream_t stream) {
    const float* x    = (const float*)d_in[0];
    const float* mask = (const float*)d_in[1];
    const float* W_w  = (const float*)d_in[2];
    const float* W_b  = (const float*)d_in[3];
    const float* U_w  = (const float*)d_in[4];
    const float* U_b  = (const float*)d_in[5];
    const float* v_w  = (const float*)d_in[6];
    const float* v_b  = (const float*)d_in[7];
    const float* m    = (const float*)d_in[8];
    float* out = (float*)d_out;

    float* ws     = (float*)d_ws;
    float* y_part = ws;                              // NFQ*B*H*T = 819200 floats
    float* u_buf  = ws + NFQ * B * H * T;            // NCL*H

    proj_u_kernel<<<dim3(17, B), 256, 0, stream>>>(x, W_w, U_w, U_b, m, y_part, u_buf);
    wgate_e_kernel<<<B * S, 256, 0, stream>>>(y_part, mask, W_b, u_buf, v_w, v_b, m, out);
}

// Round 15
// 82.967 us; speedup vs baseline: 1.3354x; 1.3354x over previous
//
#include <hip/hip_runtime.h>
#include <hip/hip_bf16.h>
#include <math.h>

#define B 32
#define S 8
#define FEA 2560
#define T 800
#define NCL 512
#define EMB 256
#define H 8

#define BF 64            // features per block (16 per wave)
#define SEC 128          // k floats per staged section
#define NSEC 6           // full sections (k 0..767); tail 32 via direct-global MFMA
#define MROWB 1664       // bytes per mask row in LDS (1600 data + 64 pad)

typedef __attribute__((ext_vector_type(8))) short bf16x8;
typedef __attribute__((ext_vector_type(4))) float f32x4;

__device__ __forceinline__ short4 cvt_bf16x4(float4 v) {
    union { short4 s4; __hip_bfloat162 h[2]; } u;
    u.h[0] = __float22bfloat162_rn(make_float2(v.x, v.y));
    u.h[1] = __float22bfloat162_rn(make_float2(v.z, v.w));
    return u.s4;
}

// Stage: thread covers rows r*8+(tid>>5), cols [(tid&31)*4, +4) of the 128-float
// section window -> each wave instruction = 8 rows x 512 B contiguous runs.
#define LOAD_SEC(s) {                                                               \
    _Pragma("unroll")                                                               \
    for (int r = 0; r < 8; ++r)                                                     \
        R[r] = *(const float4*)(xb + (size_t)(f0 + r * 8 + (tid >> 5)) * T          \
                                + (s) * SEC + (tid & 31) * 4);                      \
}

#define WRITE_SEC() {                                                               \
    _Pragma("unroll")                                                               \
    for (int r = 0; r < 8; ++r) {                                                   \
        const int row_ = r * 8 + (tid >> 5);                                        \
        *(short4*)(xls + row_ * 256 + (((tid & 31) * 8) ^ ((row_ & 7) << 4)))       \
            = cvt_bf16x4(R[r]);                                                     \
    }                                                                               \
}

// One MFMA step (32 k) of section sec, step st in 0..3.
#define CSTEP(sec, st) {                                                            \
    const bf16x8 bx_ = *(const bf16x8*)(xls + xrow * 256                            \
                          + ((((st) & 3) * 64 + kb16) ^ xswz));                     \
    const bf16x8 am_ = *(const bf16x8*)((const char*)mask_l + mbase                 \
                          + ((((sec) * 4 + (st)) * 64 + kb16) ^ mswz));             \
    acc = __builtin_amdgcn_mfma_f32_16x16x32_bf16(am_, bx_, acc, 0, 0, 0);          \
}

#define CSEC(sec) { CSTEP(sec,0) CSTEP(sec,1) CSTEP(sec,2) CSTEP(sec,3) }

// ---------------- Kernel A: pooled via MFMA; 5 blocks/CU, single x-buffer ----------------
// grid (41, 32): x<40 pool tiles, x==40 & b<8 -> u blocks.  (identical to r13 best)
__global__ __launch_bounds__(256, 5) void pool_u_kernel(const float* __restrict__ x,
                                                        const float* __restrict__ mask,
                                                        const float* __restrict__ U_w,
                                                        const float* __restrict__ U_b,
                                                        const float* __restrict__ m,
                                                        float* __restrict__ pooled,
                                                        float* __restrict__ u_out) {
    const int b = blockIdx.y;

    if (blockIdx.x == FEA / BF) {
        if (b >= 8) return;
        const int n  = b * 64 + (threadIdx.x >> 2);
        const int h0 = (threadIdx.x & 3) * 2;
        float a0 = 0.f, a1 = 0.f;
        #pragma unroll 4
        for (int e = 0; e < EMB; ++e) {
            const float mv = m[n * EMB + e];
            a0 += mv * U_w[h0 * EMB + e];
            a1 += mv * U_w[(h0 + 1) * EMB + e];
        }
        u_out[n * H + h0]     = a0 + U_b[h0];
        u_out[n * H + h0 + 1] = a1 + U_b[h0 + 1];
        return;
    }

    __shared__ short mask_l[S * (MROWB / 2)];   // 13312 B
    __shared__ char  xls[16384];                // single 64-row x 256 B section buffer

    const int tid = threadIdx.x;
    const int f0  = blockIdx.x * BF;
    const float* xb = x + (size_t)b * FEA * T;

    float4 R[8];

    // ---- prologue: issue sec-0 loads; stage mask while they fly ----
    LOAD_SEC(0)

    for (int v = tid; v < S * 200; v += 256) {
        const int s = v / 200, c4 = v % 200;
        const float4 mv = *(const float4*)(mask + ((size_t)(b * S + s)) * T + c4 * 4);
        const int byte = s * MROWB + ((c4 * 8) ^ (s << 4));
        *(short4*)((char*)mask_l + byte) = cvt_bf16x4(mv);
    }

    WRITE_SEC()              // sec 0 -> LDS (vmcnt waits R only)
    LOAD_SEC(1)              // flies across barrier + sec-0 compute
    __syncthreads();         // mask + sec 0 visible

    // compute-side mapping
    const int wave = tid >> 6, lane = tid & 63;
    const int kb16 = (lane >> 4) * 16;
    const int xrow = wave * 16 + (lane & 15);
    const int xswz = (xrow & 7) << 4;
    const int srow = lane & 7;
    const int mbase = srow * MROWB;
    const int mswz = srow << 4;

    f32x4 acc = {0.f, 0.f, 0.f, 0.f};

    // ---- main loop: single buffer, 2 barriers/section, reg-prefetch one section ahead ----
    #pragma unroll 1
    for (int sec = 0; sec < NSEC; ++sec) {
        CSEC(sec)
        __syncthreads();                 // all reads of sec done
        if (sec < NSEC - 1) {
            WRITE_SEC()                  // sec+1 (R loaded one phase ago)
            if (sec < NSEC - 2) LOAD_SEC(sec + 2)
        }
        __syncthreads();                 // writes visible
    }

    // ---- tail: k 768..799 — x direct from global, mask from LDS (kstep = 24) ----
    {
        const float* xt = xb + (size_t)(f0 + xrow) * T + 768 + (lane >> 4) * 8;
        const float4 t0 = *(const float4*)(xt);
        const float4 t1 = *(const float4*)(xt + 4);
        union { bf16x8 v; short4 s4[2]; } Bx;
        Bx.s4[0] = cvt_bf16x4(t0);
        Bx.s4[1] = cvt_bf16x4(t1);
        const bf16x8 am = *(const bf16x8*)((const char*)mask_l + mbase
                              + ((24 * 64 + kb16) ^ mswz));
        acc = __builtin_amdgcn_mfma_f32_16x16x32_bf16(am, Bx.v, acc, 0, 0, 0);
    }

    // C/D layout: col = lane&15, row = (lane>>4)*4 + i. Rows 0..7 = speakers.
    if (lane < 32) {
        const int col = lane & 15;
        #pragma unroll
        for (int i = 0; i < 4; ++i) {
            const int sr = (lane >> 4) * 4 + i;
            pooled[(size_t)(b * S + sr) * FEA + f0 + wave * 16 + col] = acc[i];
        }
    }
}

// ---------------- Kernel B: fused per-(b,s) epilogue: denom, w, gate, e = a @ m ----------------
__global__ __launch_bounds__(256) void fused_epi_kernel(const float* __restrict__ pooled,
                                                        const float* __restrict__ mask,
                                                        const float* __restrict__ W_w,
                                                        const float* __restrict__ W_b,
                                                        const float* __restrict__ u_buf,
                                                        const float* __restrict__ v_w,
                                                        const float* __restrict__ v_b,
                                                        const float* __restrict__ m,
                                                        float* __restrict__ out) {
    __shared__ float red[256];
    __shared__ float wred[4][8];
    __shared__ float w_sh[8];
    __shared__ float a_lds[NCL];

    const int bs  = blockIdx.x;
    const int tid = threadIdx.x;
    const int lane = tid & 63, wave = tid >> 6;

    // denom = sum_t mask[b,s,t]
    float p = 0.f;
    for (int t = tid; t < T; t += 256) p += mask[(size_t)bs * T + t];
    red[tid] = p;
    __syncthreads();
    for (int st = 128; st > 0; st >>= 1) {
        if (tid < st) red[tid] += red[tid + st];
        __syncthreads();
    }
    const float inv_d = 1.f / (red[0] + 1e-10f);

    // w[h] = (pooled[b,s,:] * inv_d) @ W_w[h,:] + W_b[h]
    float acc[8];
    #pragma unroll
    for (int h = 0; h < 8; ++h) acc[h] = 0.f;
    for (int f = tid; f < FEA; f += 256) {
        const float xv = pooled[(size_t)bs * FEA + f] * inv_d;
        #pragma unroll
        for (int h = 0; h < 8; ++h) acc[h] += xv * W_w[h * FEA + f];
    }
    #pragma unroll
    for (int h = 0; h < 8; ++h) {
        float v = acc[h];
        #pragma unroll
        for (int off = 32; off > 0; off >>= 1) v += __shfl_xor(v, off, 64);
        if (lane == 0) wred[wave][h] = v;
    }
    __syncthreads();
    if (tid < 8)
        w_sh[tid] = wred[0][tid] + wred[1][tid] + wred[2][tid] + wred[3][tid] + W_b[tid];
    __syncthreads();

    // gate: a[n] = sigmoid(sum_h tanh(w[h]+u[n,h])*v_w[h] + v_b)
    const float vb = v_b[0];
    float vw[8];
    #pragma unroll
    for (int h = 0; h < 8; ++h) vw[h] = v_w[h];
    #pragma unroll
    for (int k = 0; k < 2; ++k) {
        const int n = k * 256 + tid;
        float c = vb;
        #pragma unroll
        for (int h = 0; h < 8; ++h)
            c += tanhf(w_sh[h] + u_buf[n * H + h]) * vw[h];
        a_lds[n] = 1.f / (1.f + expf(-c));
    }
    __syncthreads();

    // e[emb] = sum_n a[n] * m[n, emb]   (tid == emb, coalesced m reads, L2-hot)
    float e = 0.f;
    #pragma unroll 8
    for (int n = 0; n < NCL; ++n) e += a_lds[n] * m[n * EMB + tid];
    out[bs * EMB + tid] = e;
}

extern "C" void kernel_launch(void* const* d_in, const int* in_sizes, int n_in,
                              void* d_out, int out_size, void* d_ws, size_t ws_size,
                              hipStream_t stream) {
    const float* x    = (const float*)d_in[0];
    const float* mask = (const float*)d_in[1];
    const float* W_w  = (const float*)d_in[2];
    const float* W_b  = (const float*)d_in[3];
    const float* U_w  = (const float*)d_in[4];
    const float* U_b  = (const float*)d_in[5];
    const float* v_w  = (const float*)d_in[6];
    const float* v_b  = (const float*)d_in[7];
    const float* m    = (const float*)d_in[8];
    float* out = (float*)d_out;

    float* ws     = (float*)d_ws;
    float* pooled = ws;                          // B*S*FEA
    float* u_buf  = pooled + B * S * FEA;        // NCL*H

    pool_u_kernel<<<dim3(FEA / BF + 1, B), 256, 0, stream>>>(
        x, mask, U_w, U_b, m, pooled, u_buf);
    fused_epi_kernel<<<B * S, 256, 0, stream>>>(
        pooled, mask, W_w, W_b, u_buf, v_w, v_b, m, out);
}

// Round 16
// 67.195 us; speedup vs baseline: 1.6489x; 1.2347x over previous
//
#include <hip/hip_runtime.h>
#include <hip/hip_bf16.h>
#include <math.h>

#define B 32
#define S 8
#define FEA 2560
#define T 800
#define NCL 512
#define EMB 256
#define H 8

#define BF 64            // features per block (16 per wave)
#define SEC 128          // k floats per staged section
#define NSEC 6           // full sections (k 0..767); tail 32 via direct-global MFMA
#define MROWB 1664       // bytes per mask row in LDS (1600 data + 64 pad)

typedef __attribute__((ext_vector_type(8))) short bf16x8;
typedef __attribute__((ext_vector_type(4))) float f32x4;

__device__ __forceinline__ short4 cvt_bf16x4(float4 v) {
    union { short4 s4; __hip_bfloat162 h[2]; } u;
    u.h[0] = __float22bfloat162_rn(make_float2(v.x, v.y));
    u.h[1] = __float22bfloat162_rn(make_float2(v.z, v.w));
    return u.s4;
}

// Stage: thread covers rows r*8+(tid>>5), cols [(tid&31)*4, +4) of the 128-float
// section window -> each wave instruction = 8 rows x 512 B contiguous runs.
#define LOAD_SEC(s) {                                                               \
    _Pragma("unroll")                                                               \
    for (int r = 0; r < 8; ++r)                                                     \
        R[r] = *(const float4*)(xb + (size_t)(f0 + r * 8 + (tid >> 5)) * T          \
                                + (s) * SEC + (tid & 31) * 4);                      \
}

#define WRITE_SEC() {                                                               \
    _Pragma("unroll")                                                               \
    for (int r = 0; r < 8; ++r) {                                                   \
        const int row_ = r * 8 + (tid >> 5);                                        \
        *(short4*)(xls + row_ * 256 + (((tid & 31) * 8) ^ ((row_ & 7) << 4)))       \
            = cvt_bf16x4(R[r]);                                                     \
    }                                                                               \
}

// One MFMA step (32 k) of section sec, step st in 0..3.
#define CSTEP(sec, st) {                                                            \
    const bf16x8 bx_ = *(const bf16x8*)(xls + xrow * 256                            \
                          + ((((st) & 3) * 64 + kb16) ^ xswz));                     \
    const bf16x8 am_ = *(const bf16x8*)((const char*)mask_l + mbase                 \
                          + ((((sec) * 4 + (st)) * 64 + kb16) ^ mswz));             \
    acc = __builtin_amdgcn_mfma_f32_16x16x32_bf16(am_, bx_, acc, 0, 0, 0);          \
}

#define CSEC(sec) { CSTEP(sec,0) CSTEP(sec,1) CSTEP(sec,2) CSTEP(sec,3) }

// ---------------- Kernel A: pooled via MFMA; EXACT 1280 blocks = 5/CU, no tail ----------------
// grid (40, 32).
__global__ __launch_bounds__(256, 5) void pool_kernel(const float* __restrict__ x,
                                                      const float* __restrict__ mask,
                                                      float* __restrict__ pooled) {
    const int b = blockIdx.y;

    __shared__ short mask_l[S * (MROWB / 2)];   // 13312 B
    __shared__ char  xls[16384];                // single 64-row x 256 B section buffer

    const int tid = threadIdx.x;
    const int f0  = blockIdx.x * BF;
    const float* xb = x + (size_t)b * FEA * T;

    float4 R[8];

    // ---- prologue: issue sec-0 loads; stage mask while they fly ----
    LOAD_SEC(0)

    for (int v = tid; v < S * 200; v += 256) {
        const int s = v / 200, c4 = v % 200;
        const float4 mv = *(const float4*)(mask + ((size_t)(b * S + s)) * T + c4 * 4);
        const int byte = s * MROWB + ((c4 * 8) ^ (s << 4));
        *(short4*)((char*)mask_l + byte) = cvt_bf16x4(mv);
    }

    WRITE_SEC()              // sec 0 -> LDS (vmcnt waits R only)
    LOAD_SEC(1)              // flies across barrier + sec-0 compute
    __syncthreads();         // mask + sec 0 visible

    // compute-side mapping
    const int wave = tid >> 6, lane = tid & 63;
    const int kb16 = (lane >> 4) * 16;
    const int xrow = wave * 16 + (lane & 15);
    const int xswz = (xrow & 7) << 4;
    const int srow = lane & 7;
    const int mbase = srow * MROWB;
    const int mswz = srow << 4;

    f32x4 acc = {0.f, 0.f, 0.f, 0.f};

    // ---- main loop: single buffer, 2 barriers/section, reg-prefetch one section ahead ----
    #pragma unroll 1
    for (int sec = 0; sec < NSEC; ++sec) {
        CSEC(sec)
        __syncthreads();                 // all reads of sec done
        if (sec < NSEC - 1) {
            WRITE_SEC()                  // sec+1 (R loaded one phase ago)
            if (sec < NSEC - 2) LOAD_SEC(sec + 2)
        }
        __syncthreads();                 // writes visible
    }

    // ---- tail: k 768..799 — x direct from global, mask from LDS (kstep = 24) ----
    {
        const float* xt = xb + (size_t)(f0 + xrow) * T + 768 + (lane >> 4) * 8;
        const float4 t0 = *(const float4*)(xt);
        const float4 t1 = *(const float4*)(xt + 4);
        union { bf16x8 v; short4 s4[2]; } Bx;
        Bx.s4[0] = cvt_bf16x4(t0);
        Bx.s4[1] = cvt_bf16x4(t1);
        const bf16x8 am = *(const bf16x8*)((const char*)mask_l + mbase
                              + ((24 * 64 + kb16) ^ mswz));
        acc = __builtin_amdgcn_mfma_f32_16x16x32_bf16(am, Bx.v, acc, 0, 0, 0);
    }

    // C/D layout: col = lane&15, row = (lane>>4)*4 + i. Rows 0..7 = speakers.
    if (lane < 32) {
        const int col = lane & 15;
        #pragma unroll
        for (int i = 0; i < 4; ++i) {
            const int sr = (lane >> 4) * 4 + i;
            pooled[(size_t)(b * S + sr) * FEA + f0 + wave * 16 + col] = acc[i];
        }
    }
}

// ---------------- Kernel B1: per (b,s) denom + w (+ zero out, + 2 u-clusters) ----------------
__global__ __launch_bounds__(256) void wden_kernel(const float* __restrict__ pooled,
                                                   const float* __restrict__ mask,
                                                   const float* __restrict__ W_w,
                                                   const float* __restrict__ W_b,
                                                   const float* __restrict__ U_w,
                                                   const float* __restrict__ U_b,
                                                   const float* __restrict__ m,
                                                   float* __restrict__ w_out,
                                                   float* __restrict__ u_out,
                                                   float* __restrict__ out) {
    __shared__ float red[256];
    __shared__ float wred[4][8];
    const int bs  = blockIdx.x;
    const int tid = threadIdx.x;

    out[bs * EMB + tid] = 0.f;   // EMB == 256 == blockDim.x

    // ---- u: clusters 2bs, 2bs+1 (16 dot-256s; 16-lane groups) ----
    {
        const int job = tid >> 4, sub = tid & 15;      // job 0..15
        const int cl  = 2 * bs + (job >> 3), h = job & 7;
        float pu = 0.f;
        #pragma unroll 4
        for (int e = sub; e < EMB; e += 16)
            pu += m[cl * EMB + e] * U_w[h * EMB + e];
        #pragma unroll
        for (int off = 8; off > 0; off >>= 1) pu += __shfl_xor(pu, off, 64);
        if (sub == 0) u_out[cl * H + h] = pu + U_b[h];
    }

    // ---- denom = sum_t mask[b,s,t] ----
    float p = 0.f;
    for (int t = tid; t < T; t += 256) p += mask[(size_t)bs * T + t];
    red[tid] = p;
    __syncthreads();
    for (int st = 128; st > 0; st >>= 1) {
        if (tid < st) red[tid] += red[tid + st];
        __syncthreads();
    }
    const float inv_d = 1.f / (red[0] + 1e-10f);

    // ---- w[h] = (pooled[b,s,:] * inv_d) @ W_w[h,:] + W_b[h] ----
    float acc[8];
    #pragma unroll
    for (int h = 0; h < 8; ++h) acc[h] = 0.f;
    for (int f = tid; f < FEA; f += 256) {
        const float xv = pooled[(size_t)bs * FEA + f] * inv_d;
        #pragma unroll
        for (int h = 0; h < 8; ++h) acc[h] += xv * W_w[h * FEA + f];
    }
    const int lane = tid & 63, wave = tid >> 6;
    #pragma unroll
    for (int h = 0; h < 8; ++h) {
        float v = acc[h];
        #pragma unroll
        for (int off = 32; off > 0; off >>= 1) v += __shfl_xor(v, off, 64);
        if (lane == 0) wred[wave][h] = v;
    }
    __syncthreads();
    if (tid < 8)
        w_out[bs * H + tid] = wred[0][tid] + wred[1][tid] + wred[2][tid] + wred[3][tid] + W_b[tid];
}

// ---------------- Kernel B2: fused gate + e = a @ m (n-split, atomic accumulate) ----------------
__global__ __launch_bounds__(256) void egemv_kernel(const float* __restrict__ w_buf,
                                                    const float* __restrict__ u_buf,
                                                    const float* __restrict__ v_w,
                                                    const float* __restrict__ v_b,
                                                    const float* __restrict__ m,
                                                    float* __restrict__ out) {
    __shared__ float a_sh[256];
    const int bs = blockIdx.x >> 1, half = blockIdx.x & 1;
    const int tid = threadIdx.x;
    const int n = half * 256 + tid;

    float c = v_b[0];
    #pragma unroll
    for (int h = 0; h < 8; ++h)
        c += tanhf(w_buf[bs * H + h] + u_buf[n * H + h]) * v_w[h];
    a_sh[tid] = 1.f / (1.f + expf(-c));
    __syncthreads();

    float acc = 0.f;
    #pragma unroll 8
    for (int n2 = 0; n2 < 256; ++n2)
        acc += a_sh[n2] * m[(half * 256 + n2) * EMB + tid];
    atomicAdd(&out[bs * EMB + tid], acc);
}

extern "C" void kernel_launch(void* const* d_in, const int* in_sizes, int n_in,
                              void* d_out, int out_size, void* d_ws, size_t ws_size,
                              hipStream_t stream) {
    const float* x    = (const float*)d_in[0];
    const float* mask = (const float*)d_in[1];
    const float* W_w  = (const float*)d_in[2];
    const float* W_b  = (const float*)d_in[3];
    const float* U_w  = (const float*)d_in[4];
    const float* U_b  = (const float*)d_in[5];
    const float* v_w  = (const float*)d_in[6];
    const float* v_b  = (const float*)d_in[7];
    const float* m    = (const float*)d_in[8];
    float* out = (float*)d_out;

    float* ws     = (float*)d_ws;
    float* pooled = ws;                          // B*S*FEA
    float* u_buf  = pooled + B * S * FEA;        // NCL*H
    float* w_buf  = u_buf + NCL * H;             // B*S*H

    pool_kernel<<<dim3(FEA / BF, B), 256, 0, stream>>>(x, mask, pooled);
    wden_kernel<<<B * S, 256, 0, stream>>>(pooled, mask, W_w, W_b, U_w, U_b, m,
                                           w_buf, u_buf, out);
    egemv_kernel<<<B * S * 2, 256, 0, stream>>>(w_buf, u_buf, v_w, v_b, m, out);
}

// Round 17
// 60.673 us; speedup vs baseline: 1.8261x; 1.1075x over previous
//
#include <hip/hip_runtime.h>
#include <hip/hip_bf16.h>
#include <math.h>

#define B 32
#define S 8
#define FEA 2560
#define T 800
#define NCL 512
#define EMB 256
#define H 8

#define BF 64            // features per block (16 per wave)
#define SEC 128          // k floats per staged section
#define NSEC 6           // full sections (k 0..767); tail 32 via direct-global MFMA
#define MROWB 1664       // bytes per mask row in LDS (1600 data + 64 pad)

typedef __attribute__((ext_vector_type(8))) short bf16x8;
typedef __attribute__((ext_vector_type(4))) float f32x4;

__device__ __forceinline__ short4 cvt_bf16x4(float4 v) {
    union { short4 s4; __hip_bfloat162 h[2]; } u;
    u.h[0] = __float22bfloat162_rn(make_float2(v.x, v.y));
    u.h[1] = __float22bfloat162_rn(make_float2(v.z, v.w));
    return u.s4;
}

// Stage: thread covers rows r*8+(tid>>5), cols [(tid&31)*4, +4) of the 128-float
// section window -> each wave instruction = 8 rows x 512 B contiguous runs.
#define LOAD_SEC(s) {                                                               \
    _Pragma("unroll")                                                               \
    for (int r = 0; r < 8; ++r)                                                     \
        R[r] = *(const float4*)(xb + (size_t)(f0 + r * 8 + (tid >> 5)) * T          \
                                + (s) * SEC + (tid & 31) * 4);                      \
}

#define WRITE_SEC() {                                                               \
    _Pragma("unroll")                                                               \
    for (int r = 0; r < 8; ++r) {                                                   \
        const int row_ = r * 8 + (tid >> 5);                                        \
        *(short4*)(xls + row_ * 256 + (((tid & 31) * 8) ^ ((row_ & 7) << 4)))       \
            = cvt_bf16x4(R[r]);                                                     \
    }                                                                               \
}

// One MFMA step (32 k) of section sec, step st in 0..3.
#define CSTEP(sec, st) {                                                            \
    const bf16x8 bx_ = *(const bf16x8*)(xls + xrow * 256                            \
                          + ((((st) & 3) * 64 + kb16) ^ xswz));                     \
    const bf16x8 am_ = *(const bf16x8*)((const char*)mask_l + mbase                 \
                          + ((((sec) * 4 + (st)) * 64 + kb16) ^ mswz));             \
    acc = __builtin_amdgcn_mfma_f32_16x16x32_bf16(am_, bx_, acc, 0, 0, 0);          \
}

#define CSEC(sec) { CSTEP(sec,0) CSTEP(sec,1) CSTEP(sec,2) CSTEP(sec,3) }

// ---------------- Kernel A: pooled via MFMA; EXACT 1280 blocks = 5/CU, no tail ----------------
// (identical to r16 winner)
__global__ __launch_bounds__(256, 5) void pool_kernel(const float* __restrict__ x,
                                                      const float* __restrict__ mask,
                                                      float* __restrict__ pooled) {
    const int b = blockIdx.y;

    __shared__ short mask_l[S * (MROWB / 2)];   // 13312 B
    __shared__ char  xls[16384];                // single 64-row x 256 B section buffer

    const int tid = threadIdx.x;
    const int f0  = blockIdx.x * BF;
    const float* xb = x + (size_t)b * FEA * T;

    float4 R[8];

    LOAD_SEC(0)

    for (int v = tid; v < S * 200; v += 256) {
        const int s = v / 200, c4 = v % 200;
        const float4 mv = *(const float4*)(mask + ((size_t)(b * S + s)) * T + c4 * 4);
        const int byte = s * MROWB + ((c4 * 8) ^ (s << 4));
        *(short4*)((char*)mask_l + byte) = cvt_bf16x4(mv);
    }

    WRITE_SEC()
    LOAD_SEC(1)
    __syncthreads();

    const int wave = tid >> 6, lane = tid & 63;
    const int kb16 = (lane >> 4) * 16;
    const int xrow = wave * 16 + (lane & 15);
    const int xswz = (xrow & 7) << 4;
    const int srow = lane & 7;
    const int mbase = srow * MROWB;
    const int mswz = srow << 4;

    f32x4 acc = {0.f, 0.f, 0.f, 0.f};

    #pragma unroll 1
    for (int sec = 0; sec < NSEC; ++sec) {
        CSEC(sec)
        __syncthreads();
        if (sec < NSEC - 1) {
            WRITE_SEC()
            if (sec < NSEC - 2) LOAD_SEC(sec + 2)
        }
        __syncthreads();
    }

    {
        const float* xt = xb + (size_t)(f0 + xrow) * T + 768 + (lane >> 4) * 8;
        const float4 t0 = *(const float4*)(xt);
        const float4 t1 = *(const float4*)(xt + 4);
        union { bf16x8 v; short4 s4[2]; } Bx;
        Bx.s4[0] = cvt_bf16x4(t0);
        Bx.s4[1] = cvt_bf16x4(t1);
        const bf16x8 am = *(const bf16x8*)((const char*)mask_l + mbase
                              + ((24 * 64 + kb16) ^ mswz));
        acc = __builtin_amdgcn_mfma_f32_16x16x32_bf16(am, Bx.v, acc, 0, 0, 0);
    }

    if (lane < 32) {
        const int col = lane & 15;
        #pragma unroll
        for (int i = 0; i < 4; ++i) {
            const int sr = (lane >> 4) * 4 + i;
            pooled[(size_t)(b * S + sr) * FEA + f0 + wave * 16 + col] = acc[i];
        }
    }
}

// ---------------- Kernel B1: per (b,s) denom + w, float4 + shfl-reduce (+ u, + zero out) ----------------
__global__ __launch_bounds__(256) void wden_kernel(const float* __restrict__ pooled,
                                                   const float* __restrict__ mask,
                                                   const float* __restrict__ W_w,
                                                   const float* __restrict__ W_b,
                                                   const float* __restrict__ U_w,
                                                   const float* __restrict__ U_b,
                                                   const float* __restrict__ m,
                                                   float* __restrict__ w_out,
                                                   float* __restrict__ u_out,
                                                   float* __restrict__ out) {
    __shared__ float dred[4];
    __shared__ float wred[4][8];
    const int bs  = blockIdx.x;
    const int tid = threadIdx.x;
    const int lane = tid & 63, wave = tid >> 6;

    out[bs * EMB + tid] = 0.f;   // zero for egemv atomics

    // ---- u: clusters 2bs, 2bs+1 (16 dot-256s; 16-lane groups) ----
    {
        const int job = tid >> 4, sub = tid & 15;
        const int cl  = 2 * bs + (job >> 3), h = job & 7;
        float pu = 0.f;
        #pragma unroll 4
        for (int e = sub; e < EMB; e += 16)
            pu += m[cl * EMB + e] * U_w[h * EMB + e];
        #pragma unroll
        for (int off = 8; off > 0; off >>= 1) pu += __shfl_xor(pu, off, 64);
        if (sub == 0) u_out[cl * H + h] = pu + U_b[h];
    }

    // ---- denom: float4 mask loads + wave shfl reduce (1 barrier) ----
    const float4* mk4 = (const float4*)(mask + (size_t)bs * T);   // 200 float4
    float p = 0.f;
    if (tid < 200) {
        const float4 v = mk4[tid];
        p = v.x + v.y + v.z + v.w;
    }
    #pragma unroll
    for (int off = 32; off > 0; off >>= 1) p += __shfl_xor(p, off, 64);
    if (lane == 0) dred[wave] = p;
    __syncthreads();
    const float inv_d = 1.f / (dred[0] + dred[1] + dred[2] + dred[3] + 1e-10f);

    // ---- w[h]: float4 pooled & W_w loads (640 float4 over 256 threads = 3 iters) ----
    const float4* p4 = (const float4*)(pooled + (size_t)bs * FEA);
    const float4* W4 = (const float4*)W_w;
    float acc[8];
    #pragma unroll
    for (int h = 0; h < 8; ++h) acc[h] = 0.f;
    #pragma unroll 1
    for (int i = tid; i < FEA / 4; i += 256) {
        float4 xv = p4[i];
        xv.x *= inv_d; xv.y *= inv_d; xv.z *= inv_d; xv.w *= inv_d;
        #pragma unroll
        for (int h = 0; h < 8; ++h) {
            const float4 wv = W4[h * (FEA / 4) + i];
            acc[h] += xv.x * wv.x + xv.y * wv.y + xv.z * wv.z + xv.w * wv.w;
        }
    }
    #pragma unroll
    for (int h = 0; h < 8; ++h) {
        float v = acc[h];
        #pragma unroll
        for (int off = 32; off > 0; off >>= 1) v += __shfl_xor(v, off, 64);
        if (lane == 0) wred[wave][h] = v;
    }
    __syncthreads();
    if (tid < 8)
        w_out[bs * H + tid] = wred[0][tid] + wred[1][tid] + wred[2][tid] + wred[3][tid] + W_b[tid];
}

// ---------------- Kernel B2: fused gate + e = a @ m, n-split x4 ----------------
__global__ __launch_bounds__(256) void egemv_kernel(const float* __restrict__ w_buf,
                                                    const float* __restrict__ u_buf,
                                                    const float* __restrict__ v_w,
                                                    const float* __restrict__ v_b,
                                                    const float* __restrict__ m,
                                                    float* __restrict__ out) {
    __shared__ float a_sh[128];
    const int bs = blockIdx.x >> 2, q = blockIdx.x & 3;
    const int tid = threadIdx.x;
    const int n0 = q * 128;

    if (tid < 128) {
        const int n = n0 + tid;
        float c = v_b[0];
        #pragma unroll
        for (int h = 0; h < 8; ++h)
            c += tanhf(w_buf[bs * H + h] + u_buf[n * H + h]) * v_w[h];
        a_sh[tid] = 1.f / (1.f + expf(-c));
    }
    __syncthreads();

    float acc = 0.f;
    #pragma unroll 8
    for (int j = 0; j < 128; ++j)
        acc += a_sh[j] * m[(n0 + j) * EMB + tid];
    atomicAdd(&out[bs * EMB + tid], acc);
}

extern "C" void kernel_launch(void* const* d_in, const int* in_sizes, int n_in,
                              void* d_out, int out_size, void* d_ws, size_t ws_size,
                              hipStream_t stream) {
    const float* x    = (const float*)d_in[0];
    const float* mask = (const float*)d_in[1];
    const float* W_w  = (const float*)d_in[2];
    const float* W_b  = (const float*)d_in[3];
    const float* U_w  = (const float*)d_in[4];
    const float* U_b  = (const float*)d_in[5];
    const float* v_w  = (const float*)d_in[6];
    const float* v_b  = (const float*)d_in[7];
    const float* m    = (const float*)d_in[8];
    float* out = (float*)d_out;

    float* ws     = (float*)d_ws;
    float* pooled = ws;                          // B*S*FEA
    float* u_buf  = pooled + B * S * FEA;        // NCL*H
    float* w_buf  = u_buf + NCL * H;             // B*S*H

    pool_kernel<<<dim3(FEA / BF, B), 256, 0, stream>>>(x, mask, pooled);
    wden_kernel<<<B * S, 256, 0, stream>>>(pooled, mask, W_w, W_b, U_w, U_b, m,
                                           w_buf, u_buf, out);
    egemv_kernel<<<B * S * 4, 256, 0, stream>>>(w_buf, u_buf, v_w, v_b, m, out);
}